// Round 12
// baseline (683.832 us; speedup 1.0000x reference)
//
#include <hip/hip_runtime.h>

typedef _Float16 f16;
typedef f16 f16x4 __attribute__((ext_vector_type(4)));
typedef f16 f16x8 __attribute__((ext_vector_type(8)));
typedef float f32x4 __attribute__((ext_vector_type(4)));

#define MFMA16(a, b, c) __builtin_amdgcn_mfma_f32_16x16x16f16((a), (b), (c), 0, 0, 0)
#define MFMA32(a, b, c) __builtin_amdgcn_mfma_f32_16x16x32_f16((a), (b), (c), 0, 0, 0)

struct Meta   { int pi[5], ci[5], ni[5]; };
struct EmbMap { int m[9]; };

// ---------------- wqkv transpose+convert ----------------
template <int CIN>
__global__ __launch_bounds__(64) void wT_kernel(const float* __restrict__ wqkv,
                                                f16* __restrict__ wqkvT) {
  int j = blockIdx.x;
  int which = j / CIN, jj = j % CIN;
  const float* src = wqkv + (long)which * CIN * CIN + jj;
  f16* dst = wqkvT + (long)j * CIN;
  for (int c = threadIdx.x; c < CIN; c += 64) dst[c] = (f16)src[(long)c * CIN];
}

// ---------------- fused out-proj weights -> wocA[k/8][CO][8] layout ----------------
template <int CIN, int CO>
__global__ __launch_bounds__(256) void woc_kernel(
    const float* __restrict__ wo, const float* __restrict__ bo,
    const float* __restrict__ cw, const float* __restrict__ cb,
    f16* __restrict__ wocA, float* __restrict__ fb) {
  __shared__ float scw[4 * CIN];
  __shared__ float red[256];
  int o = blockIdx.x;
  for (int i = threadIdx.x; i < 4 * CIN; i += 256) scw[i] = cw[(long)i * CO + o];
  __syncthreads();
  for (int pm = threadIdx.x; pm < 4 * CIN; pm += 256) {
    int p = pm / CIN, mm = pm % CIN;
    const float* wr = wo + (long)mm * CIN;
    const float* sc = scw + p * CIN;
    float s = 0.f;
    for (int c = 0; c < CIN; ++c) s += wr[c] * sc[c];
    wocA[((long)(pm >> 3) * CO + o) * 8 + (pm & 7)] = (f16)s;
  }
  float part = 0.f;
  for (int i = threadIdx.x; i < 4 * CIN; i += 256) part += bo[i % CIN] * scw[i];
  red[threadIdx.x] = part;
  __syncthreads();
  for (int st = 128; st > 0; st >>= 1) {
    if (threadIdx.x < st) red[threadIdx.x] += red[threadIdx.x + st];
    __syncthreads();
  }
  if (threadIdx.x == 0) fb[o] = cb[o] + red[0];
}

// ---------------- fused LN(+emb) + QKV projection, grid = (which*NSPLIT+half, win) --
// Column-split: each block computes SL = CIN/NSPLIT output cols of one matrix.
template <typename InT, int CIN, int NSPLIT>
__global__ __launch_bounds__(256) void lnproj_kernel(
    const InT* __restrict__ in, const float* __restrict__ emb,
    const float* __restrict__ lng, const float* __restrict__ lnb,
    const f16* __restrict__ wT, const float* __restrict__ bqkv,
    f16* __restrict__ gq, f16* __restrict__ gk, f16* __restrict__ gvt,
    EmbMap em) {
  constexpr int KS = CIN / 32;
  constexpr int SL = CIN / NSPLIT;        // output-column slice
  constexpr int NTS = SL / 16;
  constexpr int C8 = CIN / 8;
  constexpr int SL8 = SL / 8;
  constexpr int SLP = (SL & (SL - 1)) ? 128 : SL;  // pow2-padded staging width
  __shared__ f16 sB[SL * CIN];
  int which = blockIdx.x / NSPLIT;
  int half = blockIdx.x % NSPLIT;
  long win = blockIdx.y;
  long img = win >> 8;
  int wid = (int)(win & 255);
  int wy = wid >> 4, wx = wid & 15;
  int w = threadIdx.x >> 6, lane = threadIdx.x & 63;
  int r16 = lane & 15, kq = lane >> 4;
  int tok = w * 16 + r16;
  long orig = img * 16384 + (long)(wy * 8 + (tok >> 3)) * 128 + wx * 8 + (tok & 7);
  const InT* arow = in + orig * CIN + kq * 8;
  int t = (int)(img >> 1);
  const float* er = emb + (long)em.m[t] * CIN + kq * 8;

  // ---- LN + emb in registers, two-pass variance ----
  float v[KS][8];
  float s = 0.f;
#pragma unroll
  for (int ks = 0; ks < KS; ++ks) {
    f32x4 e0 = *(const f32x4*)(er + ks * 32);
    f32x4 e1 = *(const f32x4*)(er + ks * 32 + 4);
    if constexpr (sizeof(InT) == 4) {
      f32x4 x0 = *(const f32x4*)((const float*)arow + ks * 32);
      f32x4 x1 = *(const f32x4*)((const float*)arow + ks * 32 + 4);
#pragma unroll
      for (int j = 0; j < 4; ++j) { v[ks][j] = x0[j] + e0[j]; v[ks][4 + j] = x1[j] + e1[j]; }
    } else {
      f16x8 x = *(const f16x8*)((const f16*)arow + ks * 32);
#pragma unroll
      for (int j = 0; j < 4; ++j) { v[ks][j] = (float)x[j] + e0[j]; v[ks][4 + j] = (float)x[4 + j] + e1[j]; }
    }
#pragma unroll
    for (int j = 0; j < 8; ++j) s += v[ks][j];
  }
  s += __shfl_xor(s, 16);
  s += __shfl_xor(s, 32);
  float mu = s * (1.f / CIN);
  float ssd = 0.f;
#pragma unroll
  for (int ks = 0; ks < KS; ++ks)
#pragma unroll
    for (int j = 0; j < 8; ++j) { float d = v[ks][j] - mu; ssd += d * d; }
  ssd += __shfl_xor(ssd, 16);
  ssd += __shfl_xor(ssd, 32);
  float inv = rsqrtf(ssd * (1.f / CIN) + 1e-3f);
  f16x8 a[KS];
#pragma unroll
  for (int ks = 0; ks < KS; ++ks) {
    f32x4 g0 = *(const f32x4*)(lng + ks * 32 + kq * 8);
    f32x4 g1 = *(const f32x4*)(lng + ks * 32 + kq * 8 + 4);
    f32x4 b0 = *(const f32x4*)(lnb + ks * 32 + kq * 8);
    f32x4 b1 = *(const f32x4*)(lnb + ks * 32 + kq * 8 + 4);
#pragma unroll
    for (int j = 0; j < 4; ++j) {
      a[ks][j] = (f16)((v[ks][j] - mu) * inv * g0[j] + b0[j]);
      a[ks][4 + j] = (f16)((v[ks][4 + j] - mu) * inv * g1[j] + b1[j]);
    }
  }

  // ---- stage weight slice [SL rows][CIN cols], GEMM ----
  const f16* wsrc = wT + ((long)which * CIN + half * SL) * CIN;
  for (int idx = threadIdx.x; idx < SL * C8; idx += 256) {
    int j = idx / C8, c8 = idx % C8;
    f16x8 vv = *(const f16x8*)(wsrc + idx * 8);
    int off = ((j * CIN + c8 * 8) * 2) ^ ((j & 7) << 4);
    *(f16x8*)((char*)sB + off) = vv;
  }
  __syncthreads();

  f32x4 acc[NTS] = {};
#pragma unroll
  for (int ks = 0; ks < KS; ++ks) {
#pragma unroll
    for (int tt = 0; tt < NTS; ++tt) {
      int jl = tt * 16 + r16;
      int off = ((jl * CIN + ks * 32 + kq * 8) * 2) ^ ((jl & 7) << 4);
      f16x8 bb = *(const f16x8*)((char*)sB + off);
      acc[tt] = MFMA32(a[ks], bb, acc[tt]);
    }
  }
  __syncthreads();  // reuse sB as output staging

  if (which < 2) {
#pragma unroll
    for (int tt = 0; tt < NTS; ++tt) {
      float bias = bqkv[which * CIN + half * SL + tt * 16 + r16];
#pragma unroll
      for (int rg = 0; rg < 4; ++rg) {
        int r = w * 16 + kq * 4 + rg;
        int c = tt * 16 + r16;
        int off = ((r * SLP + c) * 2) ^ ((r & 7) << 4);
        *(f16*)((char*)sB + off) = (f16)(acc[tt][rg] + bias);
      }
    }
    __syncthreads();
    f16* dst = (which ? gk : gq) + win * 64 * CIN + half * SL;
    for (int idx = threadIdx.x; idx < 64 * SL8; idx += 256) {
      int r = idx / SL8, c8 = idx % SL8;
      int off = ((r * SLP + c8 * 8) * 2) ^ ((r & 7) << 4);
      f16x8 vv = *(const f16x8*)((char*)sB + off);
      *(f16x8*)(dst + r * CIN + c8 * 8) = vv;
    }
  } else {
#pragma unroll
    for (int tt = 0; tt < NTS; ++tt) {
      float bias = bqkv[2 * CIN + half * SL + tt * 16 + r16];
#pragma unroll
      for (int rg = 0; rg < 4; ++rg) {
        int c = tt * 16 + r16;
        int pos = w * 16 + kq * 4 + rg;
        int off = ((c * 64 + pos) * 2) ^ ((c & 7) << 4);
        *(f16*)((char*)sB + off) = (f16)(acc[tt][rg] + bias);
      }
    }
    __syncthreads();
    for (int c = threadIdx.x; c < SL; c += 256) {
      f16* dst = gvt + (win * CIN + half * SL + c) * 64;
#pragma unroll
      for (int p8 = 0; p8 < 8; ++p8) {
        int off = ((c * 64 + p8 * 8) * 2) ^ ((c & 7) << 4);
        *(f16x8*)(dst + p8 * 8) = *(const f16x8*)((char*)sB + off);
      }
    }
  }
}

// ---------------- attention v5: two-phase, half-LDS ----------------
// Phase ph: parts {2ph, 2ph+1}. Wave w computes part (w>>1) of the phase,
// heads {2(w&1), 2(w&1)+1} -> O[w>>1]. Barrier. All waves: down over 2*CIN k.
// dn accumulates across phases in registers.
template <int CIN, int DH, int CO>
__global__ __launch_bounds__(256) void attn4_kernel(
    const f16* __restrict__ gq, const f16* __restrict__ gk,
    const f16* __restrict__ gvt, const f16* __restrict__ wocA,
    const float* __restrict__ fb, float* __restrict__ out, Meta m) {
  constexpr int NKS = DH / 16;
  constexpr int NK8 = DH / 32;
  constexpr int NK4 = (DH % 32) / 16;
  constexpr int CO4 = CO / 4;
  constexpr int NTC = CO4 / 16;
  constexpr int NKD = 2 * CIN / 32;  // down k-steps per phase
  constexpr float scale = (DH == 16) ? 0.25f : (DH == 32) ? 0.1767766952966369f
                                                          : 0.1443375672974064f;
  constexpr float escale = scale * 1.4426950408889634f;
  __shared__ f16 O[2][64 * CIN];

  int img = blockIdx.y;
  int sidx = img >> 1, b = img & 1;
  int wid = blockIdx.x;
  int wy = wid >> 4, wx = wid & 15;
  int w = threadIdx.x >> 6, lane = threadIdx.x & 63;
  int r16 = lane & 15, kq = lane >> 4;
  int fpi = m.pi[sidx], fci = m.ci[sidx], fni = m.ni[sidx];
  char* Ob = (char*)O[w >> 1];

  f32x4 dn[NTC][4] = {};

#pragma unroll
  for (int ph = 0; ph < 2; ++ph) {
    int p = ph * 2 + (w >> 1);
    int qfr = (p == 1) ? fpi : ((p == 3) ? fni : fci);
    int kfr = (p == 0) ? fpi : ((p == 2) ? fni : fci);
    long qwin = (long)((qfr * 2 + b) * 256 + wid);
    long kwin = (long)((kfr * 2 + b) * 256 + wid);

#pragma unroll
    for (int hi = 0; hi < 2; ++hi) {
      int hh = (w & 1) * 2 + hi;
      f16x8 kf8[4][NK8 ? NK8 : 1];
      f16x4 kf4[4][NK4 ? NK4 : 1];
#pragma unroll
      for (int tj = 0; tj < 4; ++tj) {
        const f16* kb = gk + (kwin * 64 + tj * 16 + r16) * CIN + hh * DH;
        if constexpr (NK8 > 0)
#pragma unroll
          for (int n = 0; n < NK8; ++n)
            kf8[tj][n] = *(const f16x8*)(kb + n * 32 + kq * 8);
        if constexpr (NK4 > 0)
#pragma unroll
          for (int n = 0; n < NK4; ++n)
            kf4[tj][n] = *(const f16x4*)(kb + NK8 * 32 + n * 16 + kq * 4);
      }
      f16x4 va[NKS][4];
#pragma unroll
      for (int dt = 0; dt < NKS; ++dt)
#pragma unroll
        for (int jt = 0; jt < 4; ++jt)
          va[dt][jt] = *(const f16x4*)(gvt + (kwin * CIN + hh * DH + dt * 16 + r16) * 64 +
                                       jt * 16 + kq * 4);

      f16x4 pa[4][4];
#pragma unroll
      for (int ti = 0; ti < 4; ++ti) {
        const f16* qb = gq + (qwin * 64 + ti * 16 + r16) * CIN + hh * DH;
        f32x4 s4[4] = {};
        if constexpr (NK8 > 0) {
          f16x8 qf8[NK8];
#pragma unroll
          for (int n = 0; n < NK8; ++n) qf8[n] = *(const f16x8*)(qb + n * 32 + kq * 8);
#pragma unroll
          for (int tj = 0; tj < 4; ++tj)
#pragma unroll
            for (int n = 0; n < NK8; ++n) s4[tj] = MFMA32(kf8[tj][n], qf8[n], s4[tj]);
        }
        if constexpr (NK4 > 0) {
          f16x4 qf4[NK4];
#pragma unroll
          for (int n = 0; n < NK4; ++n)
            qf4[n] = *(const f16x4*)(qb + NK8 * 32 + n * 16 + kq * 4);
#pragma unroll
          for (int tj = 0; tj < 4; ++tj)
#pragma unroll
            for (int n = 0; n < NK4; ++n) s4[tj] = MFMA16(kf4[tj][n], qf4[n], s4[tj]);
        }
        float sum = 0.f;
#pragma unroll
        for (int tj = 0; tj < 4; ++tj)
#pragma unroll
          for (int rg = 0; rg < 4; ++rg) {
            float e = __builtin_amdgcn_exp2f(s4[tj][rg] * escale);
            s4[tj][rg] = e;
            sum += e;
          }
        sum += __shfl_xor(sum, 16);
        sum += __shfl_xor(sum, 32);
        float invs = 1.f / sum;
#pragma unroll
        for (int tj = 0; tj < 4; ++tj) {
          f16x4 pv;
#pragma unroll
          for (int rg = 0; rg < 4; ++rg) pv[rg] = (f16)(s4[tj][rg] * invs);
          pa[tj][ti] = pv;
        }
      }

#pragma unroll
      for (int dt = 0; dt < NKS; ++dt) {
#pragma unroll
        for (int ti = 0; ti < 4; ++ti) {
          f32x4 po = {};
#pragma unroll
          for (int jt = 0; jt < 4; ++jt) po = MFMA16(va[dt][jt], pa[jt][ti], po);
          int i = ti * 16 + r16;
          int c0 = hh * DH + dt * 16 + kq * 4;
          f16x4 pk;
#pragma unroll
          for (int rg = 0; rg < 4; ++rg) pk[rg] = (f16)po[rg];
          int off = ((i * CIN + c0) * 2) ^ ((i & 7) << 4);
          *(f16x4*)(Ob + off) = pk;
        }
      }
    }
    __syncthreads();  // O[0..1] of this phase ready

    // ---- down over k = 2*CIN (parts 2ph, 2ph+1) ----
#pragma unroll
    for (int ck = 0; ck < NKD; ++ck) {
      int k0 = ck * 32;
      int pl = k0 / CIN;
      int c = k0 - pl * CIN;
      char* Osrc = (char*)O[pl];
      f16x8 ob[4];
#pragma unroll
      for (int ti = 0; ti < 4; ++ti) {
        int i = ti * 16 + r16;
        int off = ((i * CIN + c + kq * 8) * 2) ^ ((i & 7) << 4);
        ob[ti] = *(const f16x8*)(Osrc + off);
      }
      long pm = (long)((ph * 2 + pl) * CIN + c + kq * 8);
#pragma unroll
      for (int ot = 0; ot < NTC; ++ot) {
        f16x8 wa = *(const f16x8*)(wocA + ((pm >> 3) * CO + w * CO4 + ot * 16 + r16) * 8);
#pragma unroll
        for (int ti = 0; ti < 4; ++ti) dn[ot][ti] = MFMA32(wa, ob[ti], dn[ot][ti]);
      }
    }
    if (ph == 0) __syncthreads();  // before next phase overwrites O
  }

  // ---- store: relu(dn + fb), packed f32x4; wave w owns o-slice w*CO4 ----
#pragma unroll
  for (int ot = 0; ot < NTC; ++ot) {
    f32x4 fb4 = *(const f32x4*)(fb + w * CO4 + ot * 16 + kq * 4);
#pragma unroll
    for (int ti = 0; ti < 4; ++ti) {
      int i = ti * 16 + r16;
      long gtok = (long)img * 16384 + (wy * 8 + (i >> 3)) * 128 + wx * 8 + (i & 7);
      f32x4 vv;
#pragma unroll
      for (int rg = 0; rg < 4; ++rg) vv[rg] = fmaxf(dn[ot][ti][rg] + fb4[rg], 0.f);
      *(f32x4*)(out + gtok * CO + w * CO4 + ot * 16 + kq * 4) = vv;
    }
  }
}

// ---------------- attention v3: part-loop, wave = head; used for L2 ------
template <int CIN, int DH, int CO>
__global__ __launch_bounds__(256) void attn_kernel(
    const f16* __restrict__ gq, const f16* __restrict__ gk,
    const f16* __restrict__ gvt, const f16* __restrict__ wocA,
    const float* __restrict__ fb, float* __restrict__ out, Meta m) {
  constexpr int NKS = DH / 16;
  constexpr int NK8 = DH / 32;
  constexpr int NK4 = (DH % 32) / 16;
  constexpr int CO4 = CO / 4;
  constexpr int NTC = CO4 / 16;
  constexpr int NKD = CIN / 32;
  constexpr float scale = (DH == 16) ? 0.25f : (DH == 32) ? 0.1767766952966369f
                                                          : 0.1443375672974064f;
  constexpr float escale = scale * 1.4426950408889634f;
  __shared__ f16 O[2][64 * CIN];

  int img = blockIdx.y;
  int sidx = img >> 1, b = img & 1;
  int wid = blockIdx.x;
  int wy = wid >> 4, wx = wid & 15;
  int h = threadIdx.x >> 6, lane = threadIdx.x & 63;
  int r16 = lane & 15, kq = lane >> 4;
  int fpi = m.pi[sidx], fci = m.ci[sidx], fni = m.ni[sidx];

  f32x4 dn[NTC][4] = {};

#pragma unroll
  for (int p = 0; p < 4; ++p) {
    int qfr = (p == 1) ? fpi : ((p == 3) ? fni : fci);
    int kfr = (p == 0) ? fpi : ((p == 2) ? fni : fci);
    long qwin = (long)((qfr * 2 + b) * 256 + wid);
    long kwin = (long)((kfr * 2 + b) * 256 + wid);

    f16x8 kf8[4][NK8 ? NK8 : 1];
    f16x4 kf4[4][NK4 ? NK4 : 1];
#pragma unroll
    for (int tj = 0; tj < 4; ++tj) {
      const f16* kb = gk + (kwin * 64 + tj * 16 + r16) * CIN + h * DH;
      if constexpr (NK8 > 0)
#pragma unroll
        for (int n = 0; n < NK8; ++n)
          kf8[tj][n] = *(const f16x8*)(kb + n * 32 + kq * 8);
      if constexpr (NK4 > 0)
#pragma unroll
        for (int n = 0; n < NK4; ++n)
          kf4[tj][n] = *(const f16x4*)(kb + NK8 * 32 + n * 16 + kq * 4);
    }
    f16x4 va[NKS][4];
#pragma unroll
    for (int dt = 0; dt < NKS; ++dt)
#pragma unroll
      for (int jt = 0; jt < 4; ++jt)
        va[dt][jt] = *(const f16x4*)(gvt + (kwin * CIN + h * DH + dt * 16 + r16) * 64 +
                                     jt * 16 + kq * 4);

    f16x4 pa[4][4];
#pragma unroll
    for (int ti = 0; ti < 4; ++ti) {
      const f16* qb = gq + (qwin * 64 + ti * 16 + r16) * CIN + h * DH;
      f32x4 s4[4] = {};
      if constexpr (NK8 > 0) {
        f16x8 qf8[NK8];
#pragma unroll
        for (int n = 0; n < NK8; ++n) qf8[n] = *(const f16x8*)(qb + n * 32 + kq * 8);
#pragma unroll
        for (int tj = 0; tj < 4; ++tj)
#pragma unroll
          for (int n = 0; n < NK8; ++n) s4[tj] = MFMA32(kf8[tj][n], qf8[n], s4[tj]);
      }
      if constexpr (NK4 > 0) {
        f16x4 qf4[NK4];
#pragma unroll
        for (int n = 0; n < NK4; ++n)
          qf4[n] = *(const f16x4*)(qb + NK8 * 32 + n * 16 + kq * 4);
#pragma unroll
        for (int tj = 0; tj < 4; ++tj)
#pragma unroll
          for (int n = 0; n < NK4; ++n) s4[tj] = MFMA16(kf4[tj][n], qf4[n], s4[tj]);
      }
      float sum = 0.f;
#pragma unroll
      for (int tj = 0; tj < 4; ++tj)
#pragma unroll
        for (int rg = 0; rg < 4; ++rg) {
          float e = __builtin_amdgcn_exp2f(s4[tj][rg] * escale);
          s4[tj][rg] = e;
          sum += e;
        }
      sum += __shfl_xor(sum, 16);
      sum += __shfl_xor(sum, 32);
      float invs = 1.f / sum;
#pragma unroll
      for (int tj = 0; tj < 4; ++tj) {
        f16x4 pv;
#pragma unroll
        for (int rg = 0; rg < 4; ++rg) pv[rg] = (f16)(s4[tj][rg] * invs);
        pa[tj][ti] = pv;
      }
    }

    char* Ob = (char*)O[p & 1];
#pragma unroll
    for (int dt = 0; dt < NKS; ++dt) {
#pragma unroll
      for (int ti = 0; ti < 4; ++ti) {
        f32x4 po = {};
#pragma unroll
        for (int jt = 0; jt < 4; ++jt) po = MFMA16(va[dt][jt], pa[jt][ti], po);
        int i = ti * 16 + r16;
        int c0 = h * DH + dt * 16 + kq * 4;
        f16x4 pk;
#pragma unroll
        for (int rg = 0; rg < 4; ++rg) pk[rg] = (f16)po[rg];
        int off = ((i * CIN + c0) * 2) ^ ((i & 7) << 4);
        *(f16x4*)(Ob + off) = pk;
      }
    }
    __syncthreads();

#pragma unroll
    for (int ck = 0; ck < NKD; ++ck) {
      f16x8 ob[4];
#pragma unroll
      for (int ti = 0; ti < 4; ++ti) {
        int i = ti * 16 + r16;
        int off = ((i * CIN + ck * 32 + kq * 8) * 2) ^ ((i & 7) << 4);
        ob[ti] = *(const f16x8*)(Ob + off);
      }
      long pm = (long)(p * CIN + ck * 32 + kq * 8);
#pragma unroll
      for (int ot = 0; ot < NTC; ++ot) {
        f16x8 wa = *(const f16x8*)(wocA + ((pm >> 3) * CO + h * CO4 + ot * 16 + r16) * 8);
#pragma unroll
        for (int ti = 0; ti < 4; ++ti) dn[ot][ti] = MFMA32(wa, ob[ti], dn[ot][ti]);
      }
    }
  }

#pragma unroll
  for (int ot = 0; ot < NTC; ++ot) {
    f32x4 fb4 = *(const f32x4*)(fb + h * CO4 + ot * 16 + kq * 4);
#pragma unroll
    for (int ti = 0; ti < 4; ++ti) {
      int i = ti * 16 + r16;
      long gtok = (long)img * 16384 + (wy * 8 + (i >> 3)) * 128 + wx * 8 + (i & 7);
      f32x4 vv;
#pragma unroll
      for (int rg = 0; rg < 4; ++rg) vv[rg] = fmaxf(dn[ot][ti][rg] + fb4[rg], 0.f);
      *(f32x4*)(out + gtok * CO + h * CO4 + ot * 16 + kq * 4) = vv;
    }
  }
}

extern "C" void kernel_launch(void* const* d_in, const int* in_sizes, int n_in,
                              void* d_out, int out_size, void* d_ws, size_t ws_size,
                              hipStream_t stream) {
  const float* x = (const float*)d_in[0];
#define PRM(l, k) ((const float*)d_in[1 + 9 * (l) + (k)])
  float* outCur = (float*)d_out;                 // [2,128,128,256]
  float* outL1 = (float*)d_out + 8388608;        // [5,2,128,128,128]

  char* ws = (char*)d_ws;
  const size_t OFF_B = 125829120ull;             // qkv arena (max 126 MB @ L1)
  const size_t OFF_W = OFF_B + 75497472ull;
  f16* qkvbase = (f16*)ws;
  float* accum1 = (float*)(ws + OFF_B);          // L1 out, fp32 [6][16384][192]
  f16* wqkvT = (f16*)(ws + OFF_W);
  f16* wocA = (f16*)(ws + OFF_W + 262144);
  float* fb = (float*)(ws + OFF_W + 262144 + 524288);

  Meta m0 = {{0, 1, 3, 5, 6}, {1, 2, 4, 6, 7}, {2, 3, 5, 7, 8}};
  Meta m1 = {{0, 1, 2, 0, 0}, {1, 2, 3, 0, 0}, {2, 3, 4, 0, 0}};
  Meta m2 = {{0, 0, 0, 0, 0}, {1, 0, 0, 0, 0}, {2, 0, 0, 0, 0}};
  EmbMap em0 = {{0, 1, 2, 3, 4, 5, 6, 7, 8}};
  EmbMap em1 = {{1, 2, 4, 6, 7, 0, 0, 0, 0}};
  EmbMap em2 = {{2, 4, 6, 0, 0, 0, 0, 0, 0}};

  // ---------------- Level 0: CIN=64, DH=16, CO=128, TL=9, S=5 ----------------
  {
    constexpr int CIN = 64, DH = 16, CO = 128, TL = 9, S = 5;
    long ntok = (long)TL * 2 * 16384;
    f16 *gq = qkvbase, *gk = gq + ntok * CIN, *gvt = gk + ntok * CIN;
    wT_kernel<CIN><<<dim3(3 * CIN), 64, 0, stream>>>(PRM(0, 3), wqkvT);
    woc_kernel<CIN, CO><<<dim3(CO), 256, 0, stream>>>(PRM(0, 5), PRM(0, 6), PRM(0, 7), PRM(0, 8), wocA, fb);
    lnproj_kernel<float, CIN, 1><<<dim3(3, (unsigned)(ntok / 64)), 256, 0, stream>>>(
        x, PRM(0, 0), PRM(0, 1), PRM(0, 2), wqkvT, PRM(0, 4), gq, gk, gvt, em0);
    attn4_kernel<CIN, DH, CO><<<dim3(256, S * 2), 256, 0, stream>>>(
        gq, gk, gvt, wocA, fb, outL1, m0);
  }
  // ---------------- Level 1: CIN=128, DH=32, CO=192, TL=5, S=3 ----------------
  {
    constexpr int CIN = 128, DH = 32, CO = 192, TL = 5, S = 3;
    long ntok = (long)TL * 2 * 16384;
    f16 *gq = qkvbase, *gk = gq + ntok * CIN, *gvt = gk + ntok * CIN;
    wT_kernel<CIN><<<dim3(3 * CIN), 64, 0, stream>>>(PRM(1, 3), wqkvT);
    woc_kernel<CIN, CO><<<dim3(CO), 256, 0, stream>>>(PRM(1, 5), PRM(1, 6), PRM(1, 7), PRM(1, 8), wocA, fb);
    lnproj_kernel<float, CIN, 1><<<dim3(3, (unsigned)(ntok / 64)), 256, 0, stream>>>(
        outL1, PRM(1, 0), PRM(1, 1), PRM(1, 2), wqkvT, PRM(1, 4), gq, gk, gvt, em1);
    attn4_kernel<CIN, DH, CO><<<dim3(256, S * 2), 256, 0, stream>>>(
        gq, gk, gvt, wocA, fb, accum1, m1);
  }
  // ---------------- Level 2: CIN=192, DH=48, CO=256, TL=3, S=1 ----------------
  {
    constexpr int CIN = 192, DH = 48, CO = 256, TL = 3, S = 1;
    long ntok = (long)TL * 2 * 16384;
    f16 *gq = qkvbase, *gk = gq + ntok * CIN, *gvt = gk + ntok * CIN;
    wT_kernel<CIN><<<dim3(3 * CIN), 64, 0, stream>>>(PRM(2, 3), wqkvT);
    woc_kernel<CIN, CO><<<dim3(CO), 256, 0, stream>>>(PRM(2, 5), PRM(2, 6), PRM(2, 7), PRM(2, 8), wocA, fb);
    lnproj_kernel<float, CIN, 2><<<dim3(6, (unsigned)(ntok / 64)), 256, 0, stream>>>(
        accum1, PRM(2, 0), PRM(2, 1), PRM(2, 2), wqkvT, PRM(2, 4), gq, gk, gvt, em2);
    attn_kernel<CIN, DH, CO><<<dim3(256, S * 2), 256, 0, stream>>>(
        gq, gk, gvt, wocA, fb, outCur, m2);
  }
#undef PRM
}

// Round 13
// 672.142 us; speedup vs baseline: 1.0174x; 1.0174x over previous
//
#include <hip/hip_runtime.h>

typedef _Float16 f16;
typedef f16 f16x4 __attribute__((ext_vector_type(4)));
typedef f16 f16x8 __attribute__((ext_vector_type(8)));
typedef float f32x4 __attribute__((ext_vector_type(4)));

#define MFMA16(a, b, c) __builtin_amdgcn_mfma_f32_16x16x16f16((a), (b), (c), 0, 0, 0)
#define MFMA32(a, b, c) __builtin_amdgcn_mfma_f32_16x16x32_f16((a), (b), (c), 0, 0, 0)

struct Meta   { int pi[5], ci[5], ni[5]; };
struct EmbMap { int m[9]; };
template <int N> struct ic { static constexpr int value = N; };

// ---------------- LayerNorm(+temporal emb) -> f16, 4 rows/block ----------------
template <int CIN>
__global__ __launch_bounds__(256) void ln_kernel(
    const float* in, long lda, const float* __restrict__ emb,
    const float* __restrict__ lng, const float* __restrict__ lnb,
    f16* out, long ldo, EmbMap em) {
  long row = (long)blockIdx.x * 4 + (threadIdx.x >> 6);
  int t = (int)(row >> 15);  // B*Y*X = 32768
  int lane = threadIdx.x & 63;
  constexpr int NCH = CIN / 64;
  const float* xr = in + row * lda;
  const float* er = emb + (long)em.m[t] * CIN;
  float v[NCH];
  float s = 0.f;
#pragma unroll
  for (int i = 0; i < NCH; ++i) { int c = lane + (i << 6); v[i] = xr[c] + er[c]; s += v[i]; }
#pragma unroll
  for (int o = 32; o >= 1; o >>= 1) s += __shfl_xor(s, o);
  float mu = s * (1.f / CIN), ss = 0.f;
#pragma unroll
  for (int i = 0; i < NCH; ++i) { float d = v[i] - mu; ss += d * d; }
#pragma unroll
  for (int o = 32; o >= 1; o >>= 1) ss += __shfl_xor(ss, o);
  float inv = rsqrtf(ss * (1.f / CIN) + 1e-3f);
  f16* orow = out + row * ldo;
#pragma unroll
  for (int i = 0; i < NCH; ++i) {
    int c = lane + (i << 6);
    orow[c] = (f16)((v[i] - mu) * inv * lng[c] + lnb[c]);
  }
}

// ---------------- wqkv transpose+convert ----------------
template <int CIN>
__global__ __launch_bounds__(64) void wT_kernel(const float* __restrict__ wqkv,
                                                f16* __restrict__ wqkvT) {
  int j = blockIdx.x;
  int which = j / CIN, jj = j % CIN;
  const float* src = wqkv + (long)which * CIN * CIN + jj;
  f16* dst = wqkvT + (long)j * CIN;
  for (int c = threadIdx.x; c < CIN; c += 64) dst[c] = (f16)src[(long)c * CIN];
}

// ---------------- fused out-proj weights -> wocA[k/8][CO][8] layout ----------------
template <int CIN, int CO>
__global__ __launch_bounds__(256) void woc_kernel(
    const float* __restrict__ wo, const float* __restrict__ bo,
    const float* __restrict__ cw, const float* __restrict__ cb,
    f16* __restrict__ wocA, float* __restrict__ fb) {
  __shared__ float scw[4 * CIN];
  __shared__ float red[256];
  int o = blockIdx.x;
  for (int i = threadIdx.x; i < 4 * CIN; i += 256) scw[i] = cw[(long)i * CO + o];
  __syncthreads();
  for (int pm = threadIdx.x; pm < 4 * CIN; pm += 256) {
    int p = pm / CIN, mm = pm % CIN;
    const float* wr = wo + (long)mm * CIN;
    const float* sc = scw + p * CIN;
    float s = 0.f;
    for (int c = 0; c < CIN; ++c) s += wr[c] * sc[c];
    wocA[((long)(pm >> 3) * CO + o) * 8 + (pm & 7)] = (f16)s;
  }
  float part = 0.f;
  for (int i = threadIdx.x; i < 4 * CIN; i += 256) part += bo[i % CIN] * scw[i];
  red[threadIdx.x] = part;
  __syncthreads();
  for (int st = 128; st > 0; st >>= 1) {
    if (threadIdx.x < st) red[threadIdx.x] += red[threadIdx.x + st];
    __syncthreads();
  }
  if (threadIdx.x == 0) fb[o] = cb[o] + red[0];
}

// ---------------- QKV projection GEMM: weights in LDS, one block = one window --
template <int CIN>
__global__ __launch_bounds__(256) void proj_kernel(
    const f16* __restrict__ cur, long lda, const f16* __restrict__ wT,
    const float* __restrict__ bqkv, f16* __restrict__ gq, f16* __restrict__ gk,
    f16* __restrict__ gvt) {
  constexpr int KS = CIN / 32;
  constexpr int NT = CIN / 16;
  constexpr int C8 = CIN / 8;
  __shared__ f16 sB[CIN * CIN];
  int which = blockIdx.x;
  long win = blockIdx.y;                 // img*256 + wid
  long img = win >> 8;
  int wid = (int)(win & 255);
  int wy = wid >> 4, wx = wid & 15;
  int w = threadIdx.x >> 6, lane = threadIdx.x & 63;
  int r16 = lane & 15, kq = lane >> 4;

  int tok = w * 16 + r16;
  long orig = img * 16384 + (long)(wy * 8 + (tok >> 3)) * 128 + wx * 8 + (tok & 7);
  const f16* arow = cur + orig * lda + kq * 8;
  f16x8 a[KS];
#pragma unroll
  for (int ks = 0; ks < KS; ++ks) a[ks] = *(const f16x8*)(arow + ks * 32);

  const f16* wsrc = wT + (long)which * CIN * CIN;
  for (int idx = threadIdx.x; idx < CIN * C8; idx += 256) {
    int j = idx / C8, c8 = idx % C8;
    f16x8 v = *(const f16x8*)(wsrc + idx * 8);
    int off = ((j * CIN + c8 * 8) * 2) ^ ((j & 7) << 4);
    *(f16x8*)((char*)sB + off) = v;
  }
  __syncthreads();

  f32x4 acc[NT] = {};
#pragma unroll
  for (int ks = 0; ks < KS; ++ks) {
#pragma unroll
    for (int t = 0; t < NT; ++t) {
      int off = (((t * 16 + r16) * CIN + ks * 32 + kq * 8) * 2) ^ ((r16 & 7) << 4);
      f16x8 bb = *(const f16x8*)((char*)sB + off);
      acc[t] = MFMA32(a[ks], bb, acc[t]);
    }
  }
  __syncthreads();  // reuse sB as output staging

  if (which < 2) {
#pragma unroll
    for (int t = 0; t < NT; ++t) {
      float bias = bqkv[which * CIN + t * 16 + r16];
#pragma unroll
      for (int rg = 0; rg < 4; ++rg) {
        int r = w * 16 + kq * 4 + rg;
        int c = t * 16 + r16;
        int off = ((r * CIN + c) * 2) ^ ((r & 7) << 4);
        *(f16*)((char*)sB + off) = (f16)(acc[t][rg] + bias);
      }
    }
    __syncthreads();
    f16* dst = (which ? gk : gq) + win * 64 * CIN;
    for (int idx = threadIdx.x; idx < 64 * C8; idx += 256) {
      int r = idx / C8, c8 = idx % C8;
      int off = ((r * CIN + c8 * 8) * 2) ^ ((r & 7) << 4);
      f16x8 v = *(const f16x8*)((char*)sB + off);
      *(f16x8*)(dst + r * CIN + c8 * 8) = v;
    }
  } else {
#pragma unroll
    for (int t = 0; t < NT; ++t) {
      float bias = bqkv[2 * CIN + t * 16 + r16];
#pragma unroll
      for (int rg = 0; rg < 4; ++rg) {
        int c = t * 16 + r16;
        int pos = w * 16 + kq * 4 + rg;
        int off = ((c * 64 + pos) * 2) ^ ((c & 7) << 4);
        *(f16*)((char*)sB + off) = (f16)(acc[t][rg] + bias);
      }
    }
    __syncthreads();
    for (int c = threadIdx.x; c < CIN; c += 256) {
      f16* dst = gvt + (win * CIN + c) * 64;
#pragma unroll
      for (int p8 = 0; p8 < 8; ++p8) {
        int off = ((c * 64 + p8 * 8) * 2) ^ ((c & 7) << 4);
        *(f16x8*)(dst + p8 * 8) = *(const f16x8*)((char*)sB + off);
      }
    }
  }
}

// ---------------- attention v3 + register-double-buffered K/V prefetch --------
// Part loop (R7 structure). If PF: after PV-write (K/V of part p dead), issue
// part p+1's K/V loads; the down-GEMM hides their latency.
template <int CIN, int DH, int CO, bool PF>
__global__ __launch_bounds__(256) void attn_kernel(
    const f16* __restrict__ gq, const f16* __restrict__ gk,
    const f16* __restrict__ gvt, const f16* __restrict__ wocA,
    const float* __restrict__ fb, float* __restrict__ out, Meta m) {
  constexpr int NKS = DH / 16;
  constexpr int NK8 = DH / 32;
  constexpr int NK4 = (DH % 32) / 16;
  constexpr int CO4 = CO / 4;
  constexpr int NTC = CO4 / 16;
  constexpr int NKD = CIN / 32;
  constexpr int NSL = PF ? 2 : 1;  // register K/V buffer slots
  constexpr float scale = (DH == 16) ? 0.25f : (DH == 32) ? 0.1767766952966369f
                                                          : 0.1443375672974064f;
  constexpr float escale = scale * 1.4426950408889634f;
  __shared__ f16 O[2][64 * CIN];

  int img = blockIdx.y;
  int sidx = img >> 1, b = img & 1;
  int wid = blockIdx.x;
  int wy = wid >> 4, wx = wid & 15;
  int h = threadIdx.x >> 6, lane = threadIdx.x & 63;
  int r16 = lane & 15, kq = lane >> 4;
  int fpi = m.pi[sidx], fci = m.ci[sidx], fni = m.ni[sidx];

  f32x4 dn[NTC][4] = {};
  f16x8 kf8[NSL][4][NK8 ? NK8 : 1];
  f16x4 kf4[NSL][4][NK4 ? NK4 : 1];
  f16x4 va[NSL][NKS][4];

  auto load_kv = [&](auto pC, auto slotC) {
    constexpr int p = decltype(pC)::value;
    constexpr int slot = decltype(slotC)::value;
    int kfr = (p == 0) ? fpi : ((p == 2) ? fni : fci);
    long kwin = (long)((kfr * 2 + b) * 256 + wid);
#pragma unroll
    for (int tj = 0; tj < 4; ++tj) {
      const f16* kb = gk + (kwin * 64 + tj * 16 + r16) * CIN + h * DH;
      if constexpr (NK8 > 0)
#pragma unroll
        for (int n = 0; n < NK8; ++n)
          kf8[slot][tj][n] = *(const f16x8*)(kb + n * 32 + kq * 8);
      if constexpr (NK4 > 0)
#pragma unroll
        for (int n = 0; n < NK4; ++n)
          kf4[slot][tj][n] = *(const f16x4*)(kb + NK8 * 32 + n * 16 + kq * 4);
    }
#pragma unroll
    for (int dt = 0; dt < NKS; ++dt)
#pragma unroll
      for (int jt = 0; jt < 4; ++jt)
        va[slot][dt][jt] = *(const f16x4*)(gvt + (kwin * CIN + h * DH + dt * 16 + r16) * 64 +
                                           jt * 16 + kq * 4);
  };

  if constexpr (PF) load_kv(ic<0>{}, ic<0>{});

  auto body = [&](auto pC) {
    constexpr int p = decltype(pC)::value;
    constexpr int slot = PF ? (p & 1) : 0;
    if constexpr (!PF) load_kv(pC, ic<0>{});
    int qfr = (p == 1) ? fpi : ((p == 3) ? fni : fci);
    long qwin = (long)((qfr * 2 + b) * 256 + wid);

    // ---- scores + softmax per ti (S^T = K*Q^T; P lane-local) ----
    f16x4 pa[4][4];  // [tj][ti]
#pragma unroll
    for (int ti = 0; ti < 4; ++ti) {
      const f16* qb = gq + (qwin * 64 + ti * 16 + r16) * CIN + h * DH;
      f32x4 s4[4] = {};
      if constexpr (NK8 > 0) {
        f16x8 qf8[NK8];
#pragma unroll
        for (int n = 0; n < NK8; ++n) qf8[n] = *(const f16x8*)(qb + n * 32 + kq * 8);
#pragma unroll
        for (int tj = 0; tj < 4; ++tj)
#pragma unroll
          for (int n = 0; n < NK8; ++n) s4[tj] = MFMA32(kf8[slot][tj][n], qf8[n], s4[tj]);
      }
      if constexpr (NK4 > 0) {
        f16x4 qf4[NK4];
#pragma unroll
        for (int n = 0; n < NK4; ++n)
          qf4[n] = *(const f16x4*)(qb + NK8 * 32 + n * 16 + kq * 4);
#pragma unroll
        for (int tj = 0; tj < 4; ++tj)
#pragma unroll
          for (int n = 0; n < NK4; ++n) s4[tj] = MFMA16(kf4[slot][tj][n], qf4[n], s4[tj]);
      }
      float sum = 0.f;
#pragma unroll
      for (int tj = 0; tj < 4; ++tj)
#pragma unroll
        for (int rg = 0; rg < 4; ++rg) {
          float e = __builtin_amdgcn_exp2f(s4[tj][rg] * escale);
          s4[tj][rg] = e;
          sum += e;
        }
      sum += __shfl_xor(sum, 16);
      sum += __shfl_xor(sum, 32);
      float invs = 1.f / sum;
#pragma unroll
      for (int tj = 0; tj < 4; ++tj) {
        f16x4 pv;
#pragma unroll
        for (int rg = 0; rg < 4; ++rg) pv[rg] = (f16)(s4[tj][rg] * invs);
        pa[tj][ti] = pv;
      }
    }

    // ---- O^T = V^T * P^T -> LDS O[p&1] (XOR-swizzled) ----
    char* Ob = (char*)O[p & 1];
#pragma unroll
    for (int dt = 0; dt < NKS; ++dt) {
#pragma unroll
      for (int ti = 0; ti < 4; ++ti) {
        f32x4 po = {};
#pragma unroll
        for (int jt = 0; jt < 4; ++jt) po = MFMA16(va[slot][dt][jt], pa[jt][ti], po);
        int i = ti * 16 + r16;
        int c0 = h * DH + dt * 16 + kq * 4;
        f16x4 pk;
#pragma unroll
        for (int rg = 0; rg < 4; ++rg) pk[rg] = (f16)po[rg];
        int off = ((i * CIN + c0) * 2) ^ ((i & 7) << 4);
        *(f16x4*)(Ob + off) = pk;
      }
    }

    // ---- prefetch next part's K/V (loads in flight across barrier+down) ----
    if constexpr (PF && p < 3) load_kv(ic<p + 1>{}, ic<(p + 1) & 1>{});

    __syncthreads();

    // ---- dn^T += woc_p^T * O^T  (MFMA32, lane-contiguous wocA reads) ----
#pragma unroll
    for (int ck = 0; ck < NKD; ++ck) {
      f16x8 ob[4];
#pragma unroll
      for (int ti = 0; ti < 4; ++ti) {
        int i = ti * 16 + r16;
        int off = ((i * CIN + ck * 32 + kq * 8) * 2) ^ ((i & 7) << 4);
        ob[ti] = *(const f16x8*)(Ob + off);
      }
      long pm = (long)(p * CIN + ck * 32 + kq * 8);
#pragma unroll
      for (int ot = 0; ot < NTC; ++ot) {
        f16x8 wa = *(const f16x8*)(wocA + ((pm >> 3) * CO + h * CO4 + ot * 16 + r16) * 8);
#pragma unroll
        for (int ti = 0; ti < 4; ++ti) dn[ot][ti] = MFMA32(wa, ob[ti], dn[ot][ti]);
      }
    }
  };
  body(ic<0>{});
  body(ic<1>{});
  body(ic<2>{});
  body(ic<3>{});

  // ---- store: relu(dn + fb), packed f32x4 ----
#pragma unroll
  for (int ot = 0; ot < NTC; ++ot) {
    f32x4 fb4 = *(const f32x4*)(fb + h * CO4 + ot * 16 + kq * 4);
#pragma unroll
    for (int ti = 0; ti < 4; ++ti) {
      int i = ti * 16 + r16;
      long gtok = (long)img * 16384 + (wy * 8 + (i >> 3)) * 128 + wx * 8 + (i & 7);
      f32x4 v;
#pragma unroll
      for (int rg = 0; rg < 4; ++rg) v[rg] = fmaxf(dn[ot][ti][rg] + fb4[rg], 0.f);
      *(f32x4*)(out + gtok * CO + h * CO4 + ot * 16 + kq * 4) = v;
    }
  }
}

extern "C" void kernel_launch(void* const* d_in, const int* in_sizes, int n_in,
                              void* d_out, int out_size, void* d_ws, size_t ws_size,
                              hipStream_t stream) {
  const float* x = (const float*)d_in[0];
#define PRM(l, k) ((const float*)d_in[1 + 9 * (l) + (k)])
  float* outCur = (float*)d_out;                 // [2,128,128,256]
  float* outL1 = (float*)d_out + 8388608;        // [5,2,128,128,128]

  char* ws = (char*)d_ws;
  const size_t OFF_B = 125829120ull;             // qkv arena
  const size_t OFF_W = OFF_B + 75497472ull;      // cur / accum1 arena
  f16* qkvbase = (f16*)ws;
  char* wsB = ws + OFF_B;
  float* accum1 = (float*)wsB;
  f16* wqkvT = (f16*)(ws + OFF_W);
  f16* wocA = (f16*)(ws + OFF_W + 262144);
  float* fb = (float*)(ws + OFF_W + 262144 + 524288);

  Meta m0 = {{0, 1, 3, 5, 6}, {1, 2, 4, 6, 7}, {2, 3, 5, 7, 8}};
  Meta m1 = {{0, 1, 2, 0, 0}, {1, 2, 3, 0, 0}, {2, 3, 4, 0, 0}};
  Meta m2 = {{0, 0, 0, 0, 0}, {1, 0, 0, 0, 0}, {2, 0, 0, 0, 0}};
  EmbMap em0 = {{0, 1, 2, 3, 4, 5, 6, 7, 8}};
  EmbMap em1 = {{1, 2, 4, 6, 7, 0, 0, 0, 0}};
  EmbMap em2 = {{2, 4, 6, 0, 0, 0, 0, 0, 0}};

  // ---------------- Level 0: CIN=64, DH=16, CO=128, TL=9, S=5 ----------------
  {
    constexpr int CIN = 64, DH = 16, CO = 128, TL = 9, S = 5;
    long ntok = (long)TL * 2 * 16384;
    f16 *gq = qkvbase, *gk = gq + ntok * CIN, *gvt = gk + ntok * CIN;
    f16* cur = (f16*)wsB;
    ln_kernel<CIN><<<dim3((unsigned)(ntok / 4)), 256, 0, stream>>>(
        x, CIN, PRM(0, 0), PRM(0, 1), PRM(0, 2), cur, CIN, em0);
    wT_kernel<CIN><<<dim3(3 * CIN), 64, 0, stream>>>(PRM(0, 3), wqkvT);
    woc_kernel<CIN, CO><<<dim3(CO), 256, 0, stream>>>(PRM(0, 5), PRM(0, 6), PRM(0, 7), PRM(0, 8), wocA, fb);
    proj_kernel<CIN><<<dim3(3, (unsigned)(ntok / 64)), 256, 0, stream>>>(
        cur, CIN, wqkvT, PRM(0, 4), gq, gk, gvt);
    attn_kernel<CIN, DH, CO, true><<<dim3(256, S * 2), 256, 0, stream>>>(
        gq, gk, gvt, wocA, fb, outL1, m0);
  }
  // ---------------- Level 1: CIN=128, DH=32, CO=192, TL=5, S=3 ----------------
  {
    constexpr int CIN = 128, DH = 32, CO = 192, TL = 5, S = 3;
    long ntok = (long)TL * 2 * 16384;
    f16 *gq = qkvbase, *gk = gq + ntok * CIN, *gvt = gk + ntok * CIN;
    f16* cur = (f16*)wsB;
    ln_kernel<CIN><<<dim3((unsigned)(ntok / 4)), 256, 0, stream>>>(
        outL1, CIN, PRM(1, 0), PRM(1, 1), PRM(1, 2), cur, CIN, em1);
    wT_kernel<CIN><<<dim3(3 * CIN), 64, 0, stream>>>(PRM(1, 3), wqkvT);
    woc_kernel<CIN, CO><<<dim3(CO), 256, 0, stream>>>(PRM(1, 5), PRM(1, 6), PRM(1, 7), PRM(1, 8), wocA, fb);
    proj_kernel<CIN><<<dim3(3, (unsigned)(ntok / 64)), 256, 0, stream>>>(
        cur, CIN, wqkvT, PRM(1, 4), gq, gk, gvt);
    attn_kernel<CIN, DH, CO, true><<<dim3(256, S * 2), 256, 0, stream>>>(
        gq, gk, gvt, wocA, fb, accum1, m1);
  }
  // ---------------- Level 2: CIN=192, DH=48, CO=256, TL=3, S=1 ----------------
  {
    constexpr int CIN = 192, DH = 48, CO = 256, TL = 3, S = 1;
    long ntok = (long)TL * 2 * 16384;
    f16 *gq = qkvbase, *gk = gq + ntok * CIN, *gvt = gk + ntok * CIN;
    f16* cur = (f16*)accum1;  // in-place LN: fp32 rows (stride 192) -> f16 (stride 384)
    ln_kernel<CIN><<<dim3((unsigned)(ntok / 4)), 256, 0, stream>>>(
        accum1, CIN, PRM(2, 0), PRM(2, 1), PRM(2, 2), cur, 384, em2);
    wT_kernel<CIN><<<dim3(3 * CIN), 64, 0, stream>>>(PRM(2, 3), wqkvT);
    woc_kernel<CIN, CO><<<dim3(CO), 256, 0, stream>>>(PRM(2, 5), PRM(2, 6), PRM(2, 7), PRM(2, 8), wocA, fb);
    proj_kernel<CIN><<<dim3(3, (unsigned)(ntok / 64)), 256, 0, stream>>>(
        cur, 384, wqkvT, PRM(2, 4), gq, gk, gvt);
    attn_kernel<CIN, DH, CO, false><<<dim3(256, S * 2), 256, 0, stream>>>(
        gq, gk, gvt, wocA, fb, outCur, m2);
  }
#undef PRM
}

// Round 14
// 647.195 us; speedup vs baseline: 1.0566x; 1.0385x over previous
//
#include <hip/hip_runtime.h>

typedef _Float16 f16;
typedef f16 f16x4 __attribute__((ext_vector_type(4)));
typedef f16 f16x8 __attribute__((ext_vector_type(8)));
typedef float f32x4 __attribute__((ext_vector_type(4)));

#define MFMA16(a, b, c) __builtin_amdgcn_mfma_f32_16x16x16f16((a), (b), (c), 0, 0, 0)
#define MFMA32(a, b, c) __builtin_amdgcn_mfma_f32_16x16x32_f16((a), (b), (c), 0, 0, 0)

struct Meta   { int pi[5], ci[5], ni[5]; };
struct EmbMap { int m[9]; };

// ---------------- LayerNorm(+temporal emb) -> f16, 4 rows/block ----------------
template <int CIN>
__global__ __launch_bounds__(256) void ln_kernel(
    const float* in, long lda, const float* __restrict__ emb,
    const float* __restrict__ lng, const float* __restrict__ lnb,
    f16* out, long ldo, EmbMap em) {
  long row = (long)blockIdx.x * 4 + (threadIdx.x >> 6);
  int t = (int)(row >> 15);  // B*Y*X = 32768
  int lane = threadIdx.x & 63;
  constexpr int NCH = CIN / 64;
  const float* xr = in + row * lda;
  const float* er = emb + (long)em.m[t] * CIN;
  float v[NCH];
  float s = 0.f;
#pragma unroll
  for (int i = 0; i < NCH; ++i) { int c = lane + (i << 6); v[i] = xr[c] + er[c]; s += v[i]; }
#pragma unroll
  for (int o = 32; o >= 1; o >>= 1) s += __shfl_xor(s, o);
  float mu = s * (1.f / CIN), ss = 0.f;
#pragma unroll
  for (int i = 0; i < NCH; ++i) { float d = v[i] - mu; ss += d * d; }
#pragma unroll
  for (int o = 32; o >= 1; o >>= 1) ss += __shfl_xor(ss, o);
  float inv = rsqrtf(ss * (1.f / CIN) + 1e-3f);
  f16* orow = out + row * ldo;
#pragma unroll
  for (int i = 0; i < NCH; ++i) {
    int c = lane + (i << 6);
    orow[c] = (f16)((v[i] - mu) * inv * lng[c] + lnb[c]);
  }
}

// ---------------- wqkv transpose+convert ----------------
template <int CIN>
__global__ __launch_bounds__(64) void wT_kernel(const float* __restrict__ wqkv,
                                                f16* __restrict__ wqkvT) {
  int j = blockIdx.x;
  int which = j / CIN, jj = j % CIN;
  const float* src = wqkv + (long)which * CIN * CIN + jj;
  f16* dst = wqkvT + (long)j * CIN;
  for (int c = threadIdx.x; c < CIN; c += 64) dst[c] = (f16)src[(long)c * CIN];
}

// ---------------- fused out-proj weights -> wocA[k/8][CO][8] layout ----------------
template <int CIN, int CO>
__global__ __launch_bounds__(256) void woc_kernel(
    const float* __restrict__ wo, const float* __restrict__ bo,
    const float* __restrict__ cw, const float* __restrict__ cb,
    f16* __restrict__ wocA, float* __restrict__ fb) {
  __shared__ float scw[4 * CIN];
  __shared__ float red[256];
  int o = blockIdx.x;
  for (int i = threadIdx.x; i < 4 * CIN; i += 256) scw[i] = cw[(long)i * CO + o];
  __syncthreads();
  for (int pm = threadIdx.x; pm < 4 * CIN; pm += 256) {
    int p = pm / CIN, mm = pm % CIN;
    const float* wr = wo + (long)mm * CIN;
    const float* sc = scw + p * CIN;
    float s = 0.f;
    for (int c = 0; c < CIN; ++c) s += wr[c] * sc[c];
    wocA[((long)(pm >> 3) * CO + o) * 8 + (pm & 7)] = (f16)s;
  }
  float part = 0.f;
  for (int i = threadIdx.x; i < 4 * CIN; i += 256) part += bo[i % CIN] * scw[i];
  red[threadIdx.x] = part;
  __syncthreads();
  for (int st = 128; st > 0; st >>= 1) {
    if (threadIdx.x < st) red[threadIdx.x] += red[threadIdx.x + st];
    __syncthreads();
  }
  if (threadIdx.x == 0) fb[o] = cb[o] + red[0];
}

// ---------------- QKV projection GEMM: weights in LDS, one block = one window --
template <int CIN>
__global__ __launch_bounds__(256) void proj_kernel(
    const f16* __restrict__ cur, long lda, const f16* __restrict__ wT,
    const float* __restrict__ bqkv, f16* __restrict__ gq, f16* __restrict__ gk,
    f16* __restrict__ gvt) {
  constexpr int KS = CIN / 32;
  constexpr int NT = CIN / 16;
  constexpr int C8 = CIN / 8;
  __shared__ f16 sB[CIN * CIN];
  int which = blockIdx.x;
  long win = blockIdx.y;                 // img*256 + wid
  long img = win >> 8;
  int wid = (int)(win & 255);
  int wy = wid >> 4, wx = wid & 15;
  int w = threadIdx.x >> 6, lane = threadIdx.x & 63;
  int r16 = lane & 15, kq = lane >> 4;

  int tok = w * 16 + r16;
  long orig = img * 16384 + (long)(wy * 8 + (tok >> 3)) * 128 + wx * 8 + (tok & 7);
  const f16* arow = cur + orig * lda + kq * 8;
  f16x8 a[KS];
#pragma unroll
  for (int ks = 0; ks < KS; ++ks) a[ks] = *(const f16x8*)(arow + ks * 32);

  const f16* wsrc = wT + (long)which * CIN * CIN;
  for (int idx = threadIdx.x; idx < CIN * C8; idx += 256) {
    int j = idx / C8, c8 = idx % C8;
    f16x8 v = *(const f16x8*)(wsrc + idx * 8);
    int off = ((j * CIN + c8 * 8) * 2) ^ ((j & 7) << 4);
    *(f16x8*)((char*)sB + off) = v;
  }
  __syncthreads();

  f32x4 acc[NT] = {};
#pragma unroll
  for (int ks = 0; ks < KS; ++ks) {
#pragma unroll
    for (int t = 0; t < NT; ++t) {
      int off = (((t * 16 + r16) * CIN + ks * 32 + kq * 8) * 2) ^ ((r16 & 7) << 4);
      f16x8 bb = *(const f16x8*)((char*)sB + off);
      acc[t] = MFMA32(a[ks], bb, acc[t]);
    }
  }
  __syncthreads();  // reuse sB as output staging

  if (which < 2) {
#pragma unroll
    for (int t = 0; t < NT; ++t) {
      float bias = bqkv[which * CIN + t * 16 + r16];
#pragma unroll
      for (int rg = 0; rg < 4; ++rg) {
        int r = w * 16 + kq * 4 + rg;
        int c = t * 16 + r16;
        int off = ((r * CIN + c) * 2) ^ ((r & 7) << 4);
        *(f16*)((char*)sB + off) = (f16)(acc[t][rg] + bias);
      }
    }
    __syncthreads();
    f16* dst = (which ? gk : gq) + win * 64 * CIN;
    for (int idx = threadIdx.x; idx < 64 * C8; idx += 256) {
      int r = idx / C8, c8 = idx % C8;
      int off = ((r * CIN + c8 * 8) * 2) ^ ((r & 7) << 4);
      f16x8 v = *(const f16x8*)((char*)sB + off);
      *(f16x8*)(dst + r * CIN + c8 * 8) = v;
    }
  } else {
#pragma unroll
    for (int t = 0; t < NT; ++t) {
      float bias = bqkv[2 * CIN + t * 16 + r16];
#pragma unroll
      for (int rg = 0; rg < 4; ++rg) {
        int c = t * 16 + r16;
        int pos = w * 16 + kq * 4 + rg;
        int off = ((c * 64 + pos) * 2) ^ ((c & 7) << 4);
        *(f16*)((char*)sB + off) = (f16)(acc[t][rg] + bias);
      }
    }
    __syncthreads();
    for (int c = threadIdx.x; c < CIN; c += 256) {
      f16* dst = gvt + (win * CIN + c) * 64;
#pragma unroll
      for (int p8 = 0; p8 < 8; ++p8) {
        int off = ((c * 64 + p8 * 8) * 2) ^ ((c & 7) << 4);
        *(f16x8*)(dst + p8 * 8) = *(const f16x8*)((char*)sB + off);
      }
    }
  }
}

// ---------------- attention v6: R7 structure, part order 0,1,3,2 ----------------
// K/V of ci loaded ONCE (parts 1 and 3 reuse registers). One barrier per part.
template <int CIN, int DH, int CO>
__global__ __launch_bounds__(256) void attn_kernel(
    const f16* __restrict__ gq, const f16* __restrict__ gk,
    const f16* __restrict__ gvt, const f16* __restrict__ wocA,
    const float* __restrict__ fb, float* __restrict__ out, Meta m) {
  constexpr int NKS = DH / 16;
  constexpr int NK8 = DH / 32;
  constexpr int NK4 = (DH % 32) / 16;
  constexpr int CO4 = CO / 4;
  constexpr int NTC = CO4 / 16;
  constexpr int NKD = CIN / 32;
  constexpr float scale = (DH == 16) ? 0.25f : (DH == 32) ? 0.1767766952966369f
                                                          : 0.1443375672974064f;
  constexpr float escale = scale * 1.4426950408889634f;
  __shared__ f16 O[2][64 * CIN];

  int img = blockIdx.y;
  int sidx = img >> 1, b = img & 1;
  int wid = blockIdx.x;
  int wy = wid >> 4, wx = wid & 15;
  int h = threadIdx.x >> 6, lane = threadIdx.x & 63;
  int r16 = lane & 15, kq = lane >> 4;
  int fpi = m.pi[sidx], fci = m.ci[sidx], fni = m.ni[sidx];

  f32x4 dn[NTC][4] = {};
  f16x8 kf8[4][NK8 ? NK8 : 1];
  f16x4 kf4[4][NK4 ? NK4 : 1];
  f16x4 va[NKS][4];

  // load K/V fragments of frame kfr into the (single) register slot
  auto load_kv = [&](int kfr) {
    long kwin = (long)((kfr * 2 + b) * 256 + wid);
#pragma unroll
    for (int tj = 0; tj < 4; ++tj) {
      const f16* kb = gk + (kwin * 64 + tj * 16 + r16) * CIN + h * DH;
      if constexpr (NK8 > 0)
#pragma unroll
        for (int n = 0; n < NK8; ++n)
          kf8[tj][n] = *(const f16x8*)(kb + n * 32 + kq * 8);
      if constexpr (NK4 > 0)
#pragma unroll
        for (int n = 0; n < NK4; ++n)
          kf4[tj][n] = *(const f16x4*)(kb + NK8 * 32 + n * 16 + kq * 4);
    }
#pragma unroll
    for (int dt = 0; dt < NKS; ++dt)
#pragma unroll
      for (int jt = 0; jt < 4; ++jt)
        va[dt][jt] = *(const f16x4*)(gvt + (kwin * CIN + h * DH + dt * 16 + r16) * 64 +
                                     jt * 16 + kq * 4);
  };

  // one part: scores(q=qfr, kv=register slot) -> softmax -> PV -> O[obuf];
  // barrier; down-GEMM with woc slice of actual part id p.
  auto run_part = [&](int p, int qfr, int obuf) {
    long qwin = (long)((qfr * 2 + b) * 256 + wid);

    f16x4 pa[4][4];  // [tj][ti]
#pragma unroll
    for (int ti = 0; ti < 4; ++ti) {
      const f16* qb = gq + (qwin * 64 + ti * 16 + r16) * CIN + h * DH;
      f32x4 s4[4] = {};
      if constexpr (NK8 > 0) {
        f16x8 qf8[NK8];
#pragma unroll
        for (int n = 0; n < NK8; ++n) qf8[n] = *(const f16x8*)(qb + n * 32 + kq * 8);
#pragma unroll
        for (int tj = 0; tj < 4; ++tj)
#pragma unroll
          for (int n = 0; n < NK8; ++n) s4[tj] = MFMA32(kf8[tj][n], qf8[n], s4[tj]);
      }
      if constexpr (NK4 > 0) {
        f16x4 qf4[NK4];
#pragma unroll
        for (int n = 0; n < NK4; ++n)
          qf4[n] = *(const f16x4*)(qb + NK8 * 32 + n * 16 + kq * 4);
#pragma unroll
        for (int tj = 0; tj < 4; ++tj)
#pragma unroll
          for (int n = 0; n < NK4; ++n) s4[tj] = MFMA16(kf4[tj][n], qf4[n], s4[tj]);
      }
      float sum = 0.f;
#pragma unroll
      for (int tj = 0; tj < 4; ++tj)
#pragma unroll
        for (int rg = 0; rg < 4; ++rg) {
          float e = __builtin_amdgcn_exp2f(s4[tj][rg] * escale);
          s4[tj][rg] = e;
          sum += e;
        }
      sum += __shfl_xor(sum, 16);
      sum += __shfl_xor(sum, 32);
      float invs = 1.f / sum;
#pragma unroll
      for (int tj = 0; tj < 4; ++tj) {
        f16x4 pv;
#pragma unroll
        for (int rg = 0; rg < 4; ++rg) pv[rg] = (f16)(s4[tj][rg] * invs);
        pa[tj][ti] = pv;
      }
    }

    char* Ob = (char*)O[obuf];
#pragma unroll
    for (int dt = 0; dt < NKS; ++dt) {
#pragma unroll
      for (int ti = 0; ti < 4; ++ti) {
        f32x4 po = {};
#pragma unroll
        for (int jt = 0; jt < 4; ++jt) po = MFMA16(va[dt][jt], pa[jt][ti], po);
        int i = ti * 16 + r16;
        int c0 = h * DH + dt * 16 + kq * 4;
        f16x4 pk;
#pragma unroll
        for (int rg = 0; rg < 4; ++rg) pk[rg] = (f16)po[rg];
        int off = ((i * CIN + c0) * 2) ^ ((i & 7) << 4);
        *(f16x4*)(Ob + off) = pk;
      }
    }
    __syncthreads();

#pragma unroll
    for (int ck = 0; ck < NKD; ++ck) {
      f16x8 ob[4];
#pragma unroll
      for (int ti = 0; ti < 4; ++ti) {
        int i = ti * 16 + r16;
        int off = ((i * CIN + ck * 32 + kq * 8) * 2) ^ ((i & 7) << 4);
        ob[ti] = *(const f16x8*)(Ob + off);
      }
      long pm = (long)(p * CIN + ck * 32 + kq * 8);
#pragma unroll
      for (int ot = 0; ot < NTC; ++ot) {
        f16x8 wa = *(const f16x8*)(wocA + ((pm >> 3) * CO + h * CO4 + ot * 16 + r16) * 8);
#pragma unroll
        for (int ti = 0; ti < 4; ++ti) dn[ot][ti] = MFMA32(wa, ob[ti], dn[ot][ti]);
      }
    }
  };

  // part order 0,1,3,2: kv=ci loaded once for parts 1 and 3
  load_kv(fpi); run_part(0, fci, 0);
  load_kv(fci); run_part(1, fpi, 1);
                run_part(3, fni, 0);
  load_kv(fni); run_part(2, fci, 1);

  // ---- store: relu(dn + fb), packed f32x4 ----
#pragma unroll
  for (int ot = 0; ot < NTC; ++ot) {
    f32x4 fb4 = *(const f32x4*)(fb + h * CO4 + ot * 16 + kq * 4);
#pragma unroll
    for (int ti = 0; ti < 4; ++ti) {
      int i = ti * 16 + r16;
      long gtok = (long)img * 16384 + (wy * 8 + (i >> 3)) * 128 + wx * 8 + (i & 7);
      f32x4 v;
#pragma unroll
      for (int rg = 0; rg < 4; ++rg) v[rg] = fmaxf(dn[ot][ti][rg] + fb4[rg], 0.f);
      *(f32x4*)(out + gtok * CO + h * CO4 + ot * 16 + kq * 4) = v;
    }
  }
}

extern "C" void kernel_launch(void* const* d_in, const int* in_sizes, int n_in,
                              void* d_out, int out_size, void* d_ws, size_t ws_size,
                              hipStream_t stream) {
  const float* x = (const float*)d_in[0];
#define PRM(l, k) ((const float*)d_in[1 + 9 * (l) + (k)])
  float* outCur = (float*)d_out;                 // [2,128,128,256]
  float* outL1 = (float*)d_out + 8388608;        // [5,2,128,128,128]

  char* ws = (char*)d_ws;
  const size_t OFF_B = 125829120ull;             // qkv arena
  const size_t OFF_W = OFF_B + 75497472ull;      // cur / accum1 arena
  f16* qkvbase = (f16*)ws;
  char* wsB = ws + OFF_B;
  float* accum1 = (float*)wsB;
  f16* wqkvT = (f16*)(ws + OFF_W);
  f16* wocA = (f16*)(ws + OFF_W + 262144);
  float* fb = (float*)(ws + OFF_W + 262144 + 524288);

  Meta m0 = {{0, 1, 3, 5, 6}, {1, 2, 4, 6, 7}, {2, 3, 5, 7, 8}};
  Meta m1 = {{0, 1, 2, 0, 0}, {1, 2, 3, 0, 0}, {2, 3, 4, 0, 0}};
  Meta m2 = {{0, 0, 0, 0, 0}, {1, 0, 0, 0, 0}, {2, 0, 0, 0, 0}};
  EmbMap em0 = {{0, 1, 2, 3, 4, 5, 6, 7, 8}};
  EmbMap em1 = {{1, 2, 4, 6, 7, 0, 0, 0, 0}};
  EmbMap em2 = {{2, 4, 6, 0, 0, 0, 0, 0, 0}};

  // ---------------- Level 0: CIN=64, DH=16, CO=128, TL=9, S=5 ----------------
  {
    constexpr int CIN = 64, DH = 16, CO = 128, TL = 9, S = 5;
    long ntok = (long)TL * 2 * 16384;
    f16 *gq = qkvbase, *gk = gq + ntok * CIN, *gvt = gk + ntok * CIN;
    f16* cur = (f16*)wsB;
    ln_kernel<CIN><<<dim3((unsigned)(ntok / 4)), 256, 0, stream>>>(
        x, CIN, PRM(0, 0), PRM(0, 1), PRM(0, 2), cur, CIN, em0);
    wT_kernel<CIN><<<dim3(3 * CIN), 64, 0, stream>>>(PRM(0, 3), wqkvT);
    woc_kernel<CIN, CO><<<dim3(CO), 256, 0, stream>>>(PRM(0, 5), PRM(0, 6), PRM(0, 7), PRM(0, 8), wocA, fb);
    proj_kernel<CIN><<<dim3(3, (unsigned)(ntok / 64)), 256, 0, stream>>>(
        cur, CIN, wqkvT, PRM(0, 4), gq, gk, gvt);
    attn_kernel<CIN, DH, CO><<<dim3(256, S * 2), 256, 0, stream>>>(
        gq, gk, gvt, wocA, fb, outL1, m0);
  }
  // ---------------- Level 1: CIN=128, DH=32, CO=192, TL=5, S=3 ----------------
  {
    constexpr int CIN = 128, DH = 32, CO = 192, TL = 5, S = 3;
    long ntok = (long)TL * 2 * 16384;
    f16 *gq = qkvbase, *gk = gq + ntok * CIN, *gvt = gk + ntok * CIN;
    f16* cur = (f16*)wsB;
    ln_kernel<CIN><<<dim3((unsigned)(ntok / 4)), 256, 0, stream>>>(
        outL1, CIN, PRM(1, 0), PRM(1, 1), PRM(1, 2), cur, CIN, em1);
    wT_kernel<CIN><<<dim3(3 * CIN), 64, 0, stream>>>(PRM(1, 3), wqkvT);
    woc_kernel<CIN, CO><<<dim3(CO), 256, 0, stream>>>(PRM(1, 5), PRM(1, 6), PRM(1, 7), PRM(1, 8), wocA, fb);
    proj_kernel<CIN><<<dim3(3, (unsigned)(ntok / 64)), 256, 0, stream>>>(
        cur, CIN, wqkvT, PRM(1, 4), gq, gk, gvt);
    attn_kernel<CIN, DH, CO><<<dim3(256, S * 2), 256, 0, stream>>>(
        gq, gk, gvt, wocA, fb, accum1, m1);
  }
  // ---------------- Level 2: CIN=192, DH=48, CO=256, TL=3, S=1 ----------------
  {
    constexpr int CIN = 192, DH = 48, CO = 256, TL = 3, S = 1;
    long ntok = (long)TL * 2 * 16384;
    f16 *gq = qkvbase, *gk = gq + ntok * CIN, *gvt = gk + ntok * CIN;
    f16* cur = (f16*)accum1;  // in-place LN: fp32 rows (stride 192) -> f16 (stride 384)
    ln_kernel<CIN><<<dim3((unsigned)(ntok / 4)), 256, 0, stream>>>(
        accum1, CIN, PRM(2, 0), PRM(2, 1), PRM(2, 2), cur, 384, em2);
    wT_kernel<CIN><<<dim3(3 * CIN), 64, 0, stream>>>(PRM(2, 3), wqkvT);
    woc_kernel<CIN, CO><<<dim3(CO), 256, 0, stream>>>(PRM(2, 5), PRM(2, 6), PRM(2, 7), PRM(2, 8), wocA, fb);
    proj_kernel<CIN><<<dim3(3, (unsigned)(ntok / 64)), 256, 0, stream>>>(
        cur, 384, wqkvT, PRM(2, 4), gq, gk, gvt);
    attn_kernel<CIN, DH, CO><<<dim3(256, S * 2), 256, 0, stream>>>(
        gq, gk, gvt, wocA, fb, outCur, m2);
  }
#undef PRM
}